// Round 6
// baseline (1982.049 us; speedup 1.0000x reference)
//
#include <hip/hip_runtime.h>
#include <math.h>

typedef unsigned long long u64;
typedef unsigned int u32;

#define BN 32
#define TN 128
#define ENCD 1024
#define HID 320
#define NG 1280       // 4*HID
#define VN 29
#define BLANKI 28
#define SLICES 8
#define UPS 40        // hidden units per slice
#define ROWS 160      // gate rows per slice (4*UPS)
#define JW 1344       // ENC+HID
#define JSTR 41       // padded LDS stride for own-slice joint weights
#define XSTRIDE 70    // u64 words per (parity,b,slice) region; 69 used
#define NPOLL (7*69)  // 483 words polled per step by waves 1-3

// workspace layout (floats)
#define E_OFF   0
#define E_SZ    (TN*BN*VN)          // 118784
#define P_OFF   (E_OFF + E_SZ)
#define P_SZ    (VN*NG)             // 37120
#define X_OFF   (P_OFF + P_SZ)      // byte 623616, 8B aligned
#define X_U64S  (2*BN*SLICES*XSTRIDE)   // 35840 u64

__device__ __forceinline__ float dot4(float4 a, float4 b) {
    return a.x*b.x + a.y*b.y + a.z*b.z + a.w*b.w;
}
__device__ __forceinline__ u64 aload(const u64* p) {
    return __hip_atomic_load(p, __ATOMIC_RELAXED, __HIP_MEMORY_SCOPE_AGENT);
}
__device__ __forceinline__ void astore(u64* p, u64 v) {
    __hip_atomic_store(p, v, __ATOMIC_RELAXED, __HIP_MEMORY_SCOPE_AGENT);
}

// K1: E[t][b][v] = b_joint[v] + x[t][b][:1024] . W_joint[v][:1024]; zeroes xchg.
__global__ __launch_bounds__(256) void k_enc(const float* __restrict__ x,
        const float* __restrict__ Wj, const float* __restrict__ bj,
        float* __restrict__ E, u64* __restrict__ xchg)
{
    __shared__ float xl[4][1056];
    const int tid = threadIdx.x;
    const int blk = blockIdx.x;
    const int t = blk >> 3, b0 = (blk & 7) * 4;

    if (tid < 35) xchg[(size_t)blk*35 + tid] = 0ull;   // 1024*35 == X_U64S

    #pragma unroll
    for (int bb = 0; bb < 4; ++bb) {
        const float4* src = (const float4*)(x + ((size_t)(t*BN + b0 + bb))*ENCD);
        float4 v4 = src[tid];
        ((float4*)&xl[bb][0])[tid + (tid >> 5)] = v4;
    }
    __syncthreads();
    if (tid < 232) {
        const int v = tid >> 3, k8 = tid & 7;
        float a0=0.f, a1=0.f, a2=0.f, a3=0.f;
        const float4* wrow = (const float4*)(Wj + (size_t)v*JW) + k8*32;
        const float4* x0 = ((const float4*)&xl[0][0]) + k8*33;
        const float4* x1 = ((const float4*)&xl[1][0]) + k8*33;
        const float4* x2 = ((const float4*)&xl[2][0]) + k8*33;
        const float4* x3 = ((const float4*)&xl[3][0]) + k8*33;
        #pragma unroll 4
        for (int m = 0; m < 32; ++m) {
            float4 w4 = wrow[m];
            a0 += dot4(w4, x0[m]);
            a1 += dot4(w4, x1[m]);
            a2 += dot4(w4, x2[m]);
            a3 += dot4(w4, x3[m]);
        }
        #pragma unroll
        for (int d = 1; d < 8; d <<= 1) {
            a0 += __shfl_xor(a0, d); a1 += __shfl_xor(a1, d);
            a2 += __shfl_xor(a2, d); a3 += __shfl_xor(a3, d);
        }
        if (k8 == 0) {
            float bjv = bj[v];
            E[((size_t)(t*BN + b0+0))*VN + v] = a0 + bjv;
            E[((size_t)(t*BN + b0+1))*VN + v] = a1 + bjv;
            E[((size_t)(t*BN + b0+2))*VN + v] = a2 + bjv;
            E[((size_t)(t*BN + b0+3))*VN + v] = a3 + bjv;
        }
    }
}

// K2: P[j][g] = b_ih[g]+b_hh[g] + emb[j] . W_ih[g]  (j==28 -> bias only / SOS)
__global__ __launch_bounds__(256) void k_pred(const float* __restrict__ emb,
        const float* __restrict__ Wih, const float* __restrict__ bih,
        const float* __restrict__ bhh, float* __restrict__ P)
{
    __shared__ float el[HID];
    const int tid = threadIdx.x, j = blockIdx.x;
    if (tid < 80) {
        float4 v4 = make_float4(0.f, 0.f, 0.f, 0.f);
        if (j < 28) v4 = ((const float4*)(emb + (size_t)j*HID))[tid];
        ((float4*)el)[tid] = v4;
    }
    __syncthreads();
    #pragma unroll
    for (int q = 0; q < 5; ++q) {
        const int r = q*256 + tid;
        float acc = bih[r] + bhh[r];
        const float4* wrow = (const float4*)(Wih + (size_t)r*HID);
        #pragma unroll 8
        for (int k4 = 0; k4 < 80; ++k4)
            acc += dot4(wrow[k4], ((const float4*)el)[k4]);
        P[(size_t)j*NG + r] = acc;
    }
}

// K3: greedy decode. 8 WGs per batch element; tagged agent-scope exchange.
// v6: speculative post-poll matvec (input is ALWAYS prev full-step's h2st),
// acc cached in regs across blanks; B_top eliminated (2 barriers/step);
// 2-deep pipelined poll sampling.
__global__ __launch_bounds__(256, 1) void k_dec(const int* __restrict__ lengths,
        const float* __restrict__ Whh, const float* __restrict__ Wj,
        const float* __restrict__ E, const float* __restrict__ P,
        u64* __restrict__ xchg, float* __restrict__ out)
{
    __shared__ float P_lds[VN*ROWS];    // 18560 B
    __shared__ float Wjh[VN*JSTR];      //  4756 B (own-slice joint weights, padded)
    __shared__ float h2st[HID];
    __shared__ float c2st[UPS];
    __shared__ float gates[ROWS];
    __shared__ float plog_l[SLICES*VN];
    __shared__ float pad_force[14400];  // total LDS > 80KB -> 1 WG/CU

    const int tid = threadIdx.x;
    const int bid = blockIdx.x;
    const int b = bid & 31, slice = bid >> 5;
    const int rg = tid >> 3, kg = tid & 7;
    const int lane = tid & 63;

    int len = lengths[b];
    if (len > TN) len = TN;
    if (len < 0) {  // never true; keeps pad_force allocated
        pad_force[tid] = (float)tid;
        gates[tid & 127] = pad_force[(tid*7) & 14399];
    }

    // --- W_hh slice into registers: 5 rows x 40 cols per thread ---
    float4 wq[50];
    #pragma unroll
    for (int q = 0; q < 5; ++q) {
        const int r = rg*5 + q;
        const int gt = r / 40, u = r - gt*40;
        const float4* wrow = (const float4*)(Whh + ((size_t)(gt*HID + slice*UPS + u))*HID + kg*40);
        #pragma unroll
        for (int jb = 0; jb < 10; ++jb) wq[q*10 + jb] = wrow[jb];
    }
    for (int i = tid; i < VN*ROWS; i += 256) {
        const int jj = i / ROWS, r = i - jj*ROWS;
        const int gt = r / 40, u = r - gt*40;
        P_lds[i] = P[(size_t)jj*NG + gt*HID + slice*UPS + u];
    }
    // own-slice joint weights, padded stride 41
    for (int i = tid; i < VN*UPS; i += 256) {
        const int v = i / UPS, k = i - v*UPS;
        Wjh[v*JSTR + k] = Wj[(size_t)v*JW + ENCD + slice*UPS + k];
    }
    if (tid < UPS) c2st[tid] = 0.f;
    if (slice == 0) for (int i = tid; i < 512; i += 256) out[b*512 + i] = -1.0f;
    __syncthreads();

    float lps = 0.f;
    float acc[5] = {0.f, 0.f, 0.f, 0.f, 0.f};   // = W_hh . h  (h starts at 0)
    int pos = 0, jrow = 28, n = 1;    // full-step sequence (0 = invalid tag)
    bool dirty = true;

    for (int t = 0; t < len; ++t) {
        const float Ereg = (lane < VN)
            ? E[((size_t)(t*BN + b))*VN + lane] : -INFINITY;

        for (int s = 0; s < 4; ++s) {
            if (dirty) {
                // ================= FULL STEP =================
                const int par = n & 1;
                const size_t mybase = ((size_t)(par*BN + b)*SLICES + slice)*XSTRIDE;
                // gates = cached acc + P[jrow]   (per-thread data only)
                if (kg == 0) {
                    #pragma unroll
                    for (int q = 0; q < 5; ++q) {
                        const int r = rg*5 + q;
                        gates[r] = acc[q] + P_lds[jrow*ROWS + r];
                    }
                }
                __syncthreads();   // B_gates
                if (tid < 64) {
                    // ---------- publisher wave ----------
                    if (tid < UPS) {
                        const float gi = gates[tid],      gf = gates[40+tid];
                        const float gg = gates[80+tid],   go = gates[120+tid];
                        const float ii = 1.f/(1.f+expf(-gi));
                        const float ff = 1.f/(1.f+expf(-gf));
                        const float oo = 1.f/(1.f+expf(-go));
                        const float G  = tanhf(gg);
                        const float c2 = ff*c2st[tid] + ii*G;
                        c2st[tid] = c2;
                        const float h2 = oo * tanhf(c2);
                        h2st[slice*UPS + tid] = h2;
                        const u64 pk = ((u64)(u32)n << 32) | (u64)__float_as_uint(h2);
                        astore(&xchg[mybase + tid], pk);
                    }
                    // own joint partial from LDS h2 (same-wave ds ordering)
                    if (tid < VN) {
                        float pkv[8];
                        #pragma unroll
                        for (int k8 = 0; k8 < 8; ++k8) {
                            float pk = 0.f;
                            #pragma unroll
                            for (int m2 = 0; m2 < 5; ++m2)
                                pk += Wjh[tid*JSTR + k8*5 + m2]
                                    * h2st[slice*UPS + k8*5 + m2];
                            pkv[k8] = pk;
                        }
                        const float pp = ((pkv[0]+pkv[1])+(pkv[2]+pkv[3]))
                                       + ((pkv[4]+pkv[5])+(pkv[6]+pkv[7]));
                        plog_l[slice*VN + tid] = pp;
                        const u64 pk2 = ((u64)(u32)n << 32) | (u64)__float_as_uint(pp);
                        astore(&xchg[mybase + UPS + tid], pk2);
                    }
                } else {
                    // ---------- poller waves (tids 64..255), 2-deep sampling ----------
                    const size_t pbase = ((size_t)(par*BN + b)*SLICES)*XSTRIDE;
                    const int i0 = tid - 64;
                    u64* ap[3]; int jj[3], ww[3]; bool need[3];
                    #pragma unroll
                    for (int r = 0; r < 3; ++r) {
                        const int i = i0 + 192*r;
                        need[r] = (i < NPOLL);
                        int j2 = 0, w = 0;
                        if (need[r]) {
                            j2 = i / 69; w = i - j2*69;
                            j2 += (j2 >= slice);
                        }
                        jj[r] = j2; ww[r] = w;
                        ap[r] = (u64*)&xchg[pbase + (size_t)j2*XSTRIDE + w];
                    }
                    u64 vc[3];
                    #pragma unroll
                    for (int r = 0; r < 3; ++r)
                        if (need[r]) vc[r] = aload(ap[r]);
                    int cap = 0;
                    while ((need[0] | need[1] | need[2]) && cap < (1 << 16)) {
                        u64 vn[3];
                        #pragma unroll
                        for (int r = 0; r < 3; ++r)        // issue next samples first
                            if (need[r]) vn[r] = aload(ap[r]);
                        #pragma unroll
                        for (int r = 0; r < 3; ++r) {      // then check current
                            if (need[r] && (u32)(vc[r] >> 32) == (u32)n) {
                                const float f = __uint_as_float((u32)vc[r]);
                                if (ww[r] < UPS) h2st[jj[r]*UPS + ww[r]] = f;
                                else             plog_l[jj[r]*VN + (ww[r]-UPS)] = f;
                                need[r] = false;
                            }
                            vc[r] = vn[r];
                        }
                        ++cap;
                    }
                }
                __syncthreads();   // B_poll: full h2st + plog_l ready
                // ---- speculative matvec for the NEXT full step: acc = W_hh . h2st
                //      (valid regardless of argmax outcome; reused across blanks) ----
                {
                    float a2[5] = {0.f, 0.f, 0.f, 0.f, 0.f};
                    #pragma unroll
                    for (int jb = 0; jb < 10; ++jb) {
                        float4 hv = *(const float4*)(h2st + kg*40 + jb*4);
                        #pragma unroll
                        for (int q = 0; q < 5; ++q) a2[q] += dot4(wq[q*10 + jb], hv);
                    }
                    #pragma unroll
                    for (int q = 0; q < 5; ++q) {
                        a2[q] += __shfl_xor(a2[q], 1);
                        a2[q] += __shfl_xor(a2[q], 2);
                        a2[q] += __shfl_xor(a2[q], 4);
                        acc[q] = a2[q];
                    }
                }
                n++;
            }
            // ============ logits -> argmax -> update ============
            float Lv;
            if (lane < VN) {
                float sA = 0.f;
                #pragma unroll
                for (int j2 = 0; j2 < SLICES; ++j2) sA += plog_l[j2*VN + lane];
                Lv = Ereg + sA;
            } else {
                Lv = -INFINITY;
            }
            float m = Lv; int ai = lane;
            #pragma unroll
            for (int d = 1; d < 64; d <<= 1) {
                const float om = __shfl_xor(m, d);
                const int   oi = __shfl_xor(ai, d);
                if (om > m || (om == m && oi < ai)) { m = om; ai = oi; }
            }
            float e = (lane < VN) ? expf(Lv - m) : 0.f;
            #pragma unroll
            for (int d = 1; d < 64; d <<= 1) e += __shfl_xor(e, d);
            lps += -logf(e);                 // v = logits[argmax] - lse

            if (ai == BLANKI) { dirty = false; break; }
            if (slice == 0 && tid == 0) out[b*512 + pos] = (float)ai;
            pos++;
            jrow = ai;
            dirty = true;
        }
    }

    if (slice == 0 && tid == 0) {
        out[16384 + b] = (float)pos;   // n_symbols
        out[16416 + b] = lps;          // logp_sum
    }
}

extern "C" void kernel_launch(void* const* d_in, const int* in_sizes, int n_in,
                              void* d_out, int out_size, void* d_ws, size_t ws_size,
                              hipStream_t stream) {
    const float* x    = (const float*)d_in[0];
    const int* lens   = (const int*)  d_in[1];
    const float* emb  = (const float*)d_in[2];
    const float* Wih  = (const float*)d_in[3];
    const float* Whh  = (const float*)d_in[4];
    const float* bih  = (const float*)d_in[5];
    const float* bhh  = (const float*)d_in[6];
    const float* Wj   = (const float*)d_in[7];
    const float* bj   = (const float*)d_in[8];
    float* out = (float*)d_out;
    float* ws  = (float*)d_ws;

    float* E    = ws + E_OFF;
    float* P    = ws + P_OFF;
    u64*   xchg = (u64*)(ws + X_OFF);

    hipLaunchKernelGGL(k_enc,  dim3(1024), dim3(256), 0, stream, x, Wj, bj, E, xchg);
    hipLaunchKernelGGL(k_pred, dim3(29),   dim3(256), 0, stream, emb, Wih, bih, bhh, P);
    hipLaunchKernelGGL(k_dec,  dim3(256),  dim3(256), 0, stream,
                       lens, Whh, Wj, E, P, xchg, out);
}

// Round 7
// 1643.177 us; speedup vs baseline: 1.2062x; 1.2062x over previous
//
#include <hip/hip_runtime.h>
#include <math.h>

typedef unsigned long long u64;
typedef unsigned int u32;

#define BN 32
#define TN 128
#define ENCD 1024
#define HID 320
#define NG 1280       // 4*HID
#define VN 29
#define BLANKI 28
#define SLICES 8
#define UPS 40        // hidden units per slice
#define ROWS 160      // gate rows per slice (4*UPS)
#define JW 1344       // ENC+HID
#define JSTR 41       // padded LDS stride for own-slice joint weights
#define XSTRIDE 70    // u64 words per (parity,b,slice) region; 69 used
#define NPOLL (7*69)  // 483 words polled per step by ALL 256 threads

// workspace layout (floats)
#define E_OFF   0
#define E_SZ    (TN*BN*VN)          // 118784
#define P_OFF   (E_OFF + E_SZ)
#define P_SZ    (VN*NG)             // 37120
#define X_OFF   (P_OFF + P_SZ)      // byte 623616, 8B aligned
#define X_U64S  (2*BN*SLICES*XSTRIDE)   // 35840 u64

__device__ __forceinline__ float dot4(float4 a, float4 b) {
    return a.x*b.x + a.y*b.y + a.z*b.z + a.w*b.w;
}
__device__ __forceinline__ u64 aload(const u64* p) {
    return __hip_atomic_load(p, __ATOMIC_RELAXED, __HIP_MEMORY_SCOPE_AGENT);
}
__device__ __forceinline__ void astore(u64* p, u64 v) {
    __hip_atomic_store(p, v, __ATOMIC_RELAXED, __HIP_MEMORY_SCOPE_AGENT);
}

// K1: E[t][b][v] = b_joint[v] + x[t][b][:1024] . W_joint[v][:1024]; zeroes xchg.
__global__ __launch_bounds__(256) void k_enc(const float* __restrict__ x,
        const float* __restrict__ Wj, const float* __restrict__ bj,
        float* __restrict__ E, u64* __restrict__ xchg)
{
    __shared__ float xl[4][1056];
    const int tid = threadIdx.x;
    const int blk = blockIdx.x;
    const int t = blk >> 3, b0 = (blk & 7) * 4;

    if (tid < 35) xchg[(size_t)blk*35 + tid] = 0ull;   // 1024*35 == X_U64S

    #pragma unroll
    for (int bb = 0; bb < 4; ++bb) {
        const float4* src = (const float4*)(x + ((size_t)(t*BN + b0 + bb))*ENCD);
        float4 v4 = src[tid];
        ((float4*)&xl[bb][0])[tid + (tid >> 5)] = v4;
    }
    __syncthreads();
    if (tid < 232) {
        const int v = tid >> 3, k8 = tid & 7;
        float a0=0.f, a1=0.f, a2=0.f, a3=0.f;
        const float4* wrow = (const float4*)(Wj + (size_t)v*JW) + k8*32;
        const float4* x0 = ((const float4*)&xl[0][0]) + k8*33;
        const float4* x1 = ((const float4*)&xl[1][0]) + k8*33;
        const float4* x2 = ((const float4*)&xl[2][0]) + k8*33;
        const float4* x3 = ((const float4*)&xl[3][0]) + k8*33;
        #pragma unroll 4
        for (int m = 0; m < 32; ++m) {
            float4 w4 = wrow[m];
            a0 += dot4(w4, x0[m]);
            a1 += dot4(w4, x1[m]);
            a2 += dot4(w4, x2[m]);
            a3 += dot4(w4, x3[m]);
        }
        #pragma unroll
        for (int d = 1; d < 8; d <<= 1) {
            a0 += __shfl_xor(a0, d); a1 += __shfl_xor(a1, d);
            a2 += __shfl_xor(a2, d); a3 += __shfl_xor(a3, d);
        }
        if (k8 == 0) {
            float bjv = bj[v];
            E[((size_t)(t*BN + b0+0))*VN + v] = a0 + bjv;
            E[((size_t)(t*BN + b0+1))*VN + v] = a1 + bjv;
            E[((size_t)(t*BN + b0+2))*VN + v] = a2 + bjv;
            E[((size_t)(t*BN + b0+3))*VN + v] = a3 + bjv;
        }
    }
}

// K2: P[j][g] = b_ih[g]+b_hh[g] + emb[j] . W_ih[g]  (j==28 -> bias only / SOS)
__global__ __launch_bounds__(256) void k_pred(const float* __restrict__ emb,
        const float* __restrict__ Wih, const float* __restrict__ bih,
        const float* __restrict__ bhh, float* __restrict__ P)
{
    __shared__ float el[HID];
    const int tid = threadIdx.x, j = blockIdx.x;
    if (tid < 80) {
        float4 v4 = make_float4(0.f, 0.f, 0.f, 0.f);
        if (j < 28) v4 = ((const float4*)(emb + (size_t)j*HID))[tid];
        ((float4*)el)[tid] = v4;
    }
    __syncthreads();
    #pragma unroll
    for (int q = 0; q < 5; ++q) {
        const int r = q*256 + tid;
        float acc = bih[r] + bhh[r];
        const float4* wrow = (const float4*)(Wih + (size_t)r*HID);
        #pragma unroll 8
        for (int k4 = 0; k4 < 80; ++k4)
            acc += dot4(wrow[k4], ((const float4*)el)[k4]);
        P[(size_t)j*NG + r] = acc;
    }
}

// K3: greedy decode. 8 WGs per batch element; tagged agent-scope exchange.
// v7: publish-first step order (gates->B->publish||poll->B->matvec->argmax),
// all-256-thread plain polling, lsum cached in registers across blanks.
__global__ __launch_bounds__(256, 1) void k_dec(const int* __restrict__ lengths,
        const float* __restrict__ Whh, const float* __restrict__ Wj,
        const float* __restrict__ E, const float* __restrict__ P,
        u64* __restrict__ xchg, float* __restrict__ out)
{
    __shared__ float P_lds[VN*ROWS];    // 18560 B
    __shared__ float Wjh[VN*JSTR];      //  4756 B (own-slice joint weights, padded)
    __shared__ float h2st[HID];
    __shared__ float c2st[UPS];
    __shared__ float gates[ROWS];
    __shared__ float plog_l[SLICES*VN];
    __shared__ float pad_force[14400];  // total LDS > 80KB -> 1 WG/CU

    const int tid = threadIdx.x;
    const int bid = blockIdx.x;
    const int b = bid & 31, slice = bid >> 5;
    const int rg = tid >> 3, kg = tid & 7;
    const int lane = tid & 63;

    int len = lengths[b];
    if (len > TN) len = TN;
    if (len < 0) {  // never true; keeps pad_force allocated
        pad_force[tid] = (float)tid;
        gates[tid & 127] = pad_force[(tid*7) & 14399];
    }

    // --- W_hh slice into registers: 5 rows x 40 cols per thread ---
    float4 wq[50];
    #pragma unroll
    for (int q = 0; q < 5; ++q) {
        const int r = rg*5 + q;
        const int gt = r / 40, u = r - gt*40;
        const float4* wrow = (const float4*)(Whh + ((size_t)(gt*HID + slice*UPS + u))*HID + kg*40);
        #pragma unroll
        for (int jb = 0; jb < 10; ++jb) wq[q*10 + jb] = wrow[jb];
    }
    for (int i = tid; i < VN*ROWS; i += 256) {
        const int jj = i / ROWS, r = i - jj*ROWS;
        const int gt = r / 40, u = r - gt*40;
        P_lds[i] = P[(size_t)jj*NG + gt*HID + slice*UPS + u];
    }
    // own-slice joint weights, padded stride 41
    for (int i = tid; i < VN*UPS; i += 256) {
        const int v = i / UPS, k = i - v*UPS;
        Wjh[v*JSTR + k] = Wj[(size_t)v*JW + ENCD + slice*UPS + k];
    }
    if (tid < UPS) c2st[tid] = 0.f;
    if (slice == 0) for (int i = tid; i < 512; i += 256) out[b*512 + i] = -1.0f;
    __syncthreads();

    float lps = 0.f;
    float acc[5] = {0.f, 0.f, 0.f, 0.f, 0.f};   // = W_hh . h  (h starts at 0)
    float lsum_r = 0.f;                          // per-lane joint hidden sum
    int pos = 0, jrow = 28, n = 1;    // full-step sequence (0 = invalid tag)
    bool dirty = true;

    // poll word assignment (fixed per thread): i1 = tid, i2 = tid + 256
    const int pw1 = tid;
    const bool has2 = (tid < NPOLL - 256);       // 227 threads carry a 2nd word

    for (int t = 0; t < len; ++t) {
        const float Ereg = (lane < VN)
            ? E[((size_t)(t*BN + b))*VN + lane] : -INFINITY;

        for (int s = 0; s < 4; ++s) {
            if (dirty) {
                // ================= FULL STEP =================
                const int par = n & 1;
                const size_t mybase = ((size_t)(par*BN + b)*SLICES + slice)*XSTRIDE;
                // gates = cached acc + P[jrow]
                if (kg == 0) {
                    #pragma unroll
                    for (int q = 0; q < 5; ++q) {
                        const int r = rg*5 + q;
                        gates[r] = acc[q] + P_lds[jrow*ROWS + r];
                    }
                }
                __syncthreads();   // B_gates
                if (tid < 64) {
                    // ---------- publisher wave ----------
                    if (tid < UPS) {
                        const float gi = gates[tid],      gf = gates[40+tid];
                        const float gg = gates[80+tid],   go = gates[120+tid];
                        const float ii = 1.f/(1.f+expf(-gi));
                        const float ff = 1.f/(1.f+expf(-gf));
                        const float oo = 1.f/(1.f+expf(-go));
                        const float G  = tanhf(gg);
                        const float c2 = ff*c2st[tid] + ii*G;
                        c2st[tid] = c2;
                        const float h2 = oo * tanhf(c2);
                        h2st[slice*UPS + tid] = h2;
                        const u64 pk = ((u64)(u32)n << 32) | (u64)__float_as_uint(h2);
                        astore(&xchg[mybase + tid], pk);
                    }
                    // own joint partial from LDS h2 (same-wave ds ordering)
                    if (tid < VN) {
                        float pkv[8];
                        #pragma unroll
                        for (int k8 = 0; k8 < 8; ++k8) {
                            float pk = 0.f;
                            #pragma unroll
                            for (int m2 = 0; m2 < 5; ++m2)
                                pk += Wjh[tid*JSTR + k8*5 + m2]
                                    * h2st[slice*UPS + k8*5 + m2];
                            pkv[k8] = pk;
                        }
                        const float pp = ((pkv[0]+pkv[1])+(pkv[2]+pkv[3]))
                                       + ((pkv[4]+pkv[5])+(pkv[6]+pkv[7]));
                        plog_l[slice*VN + tid] = pp;
                        const u64 pk2 = ((u64)(u32)n << 32) | (u64)__float_as_uint(pp);
                        astore(&xchg[mybase + UPS + tid], pk2);
                    }
                }
                // ---------- ALL threads poll (plain sampling) ----------
                {
                    const size_t pbase = ((size_t)(par*BN + b)*SLICES)*XSTRIDE;
                    int j1 = pw1 / 69; const int w1 = pw1 - j1*69;
                    j1 += (j1 >= slice);
                    u64* p1 = (u64*)&xchg[pbase + (size_t)j1*XSTRIDE + w1];
                    bool need1 = true, need2 = has2;
                    int j2 = 0, w2 = 0; u64* p2 = p1;
                    if (has2) {
                        const int i2 = tid + 256;
                        j2 = i2 / 69; w2 = i2 - j2*69;
                        j2 += (j2 >= slice);
                        p2 = (u64*)&xchg[pbase + (size_t)j2*XSTRIDE + w2];
                    }
                    int cap = 0;
                    while ((need1 | need2) && cap < (1 << 16)) {
                        u64 v1 = 0, v2 = 0;
                        if (need1) v1 = aload(p1);
                        if (need2) v2 = aload(p2);
                        if (need1 && (u32)(v1 >> 32) == (u32)n) {
                            const float f = __uint_as_float((u32)v1);
                            if (w1 < UPS) h2st[j1*UPS + w1] = f;
                            else          plog_l[j1*VN + (w1 - UPS)] = f;
                            need1 = false;
                        }
                        if (need2 && (u32)(v2 >> 32) == (u32)n) {
                            const float f = __uint_as_float((u32)v2);
                            if (w2 < UPS) h2st[j2*UPS + w2] = f;
                            else          plog_l[j2*VN + (w2 - UPS)] = f;
                            need2 = false;
                        }
                        ++cap;
                    }
                }
                __syncthreads();   // B_poll: full h2st + plog_l ready
                // ---- speculative matvec for the NEXT full step ----
                {
                    float a2[5] = {0.f, 0.f, 0.f, 0.f, 0.f};
                    #pragma unroll
                    for (int jb = 0; jb < 10; ++jb) {
                        float4 hv = *(const float4*)(h2st + kg*40 + jb*4);
                        #pragma unroll
                        for (int q = 0; q < 5; ++q) a2[q] += dot4(wq[q*10 + jb], hv);
                    }
                    #pragma unroll
                    for (int q = 0; q < 5; ++q) {
                        a2[q] += __shfl_xor(a2[q], 1);
                        a2[q] += __shfl_xor(a2[q], 2);
                        a2[q] += __shfl_xor(a2[q], 4);
                        acc[q] = a2[q];
                    }
                }
                // ---- lsum to register (cached across blank steps) ----
                if (lane < VN) {
                    float sA = 0.f;
                    #pragma unroll
                    for (int j2 = 0; j2 < SLICES; ++j2) sA += plog_l[j2*VN + lane];
                    lsum_r = sA;
                }
                n++;
            }
            // ============ logits -> argmax -> update ============
            const float Lv = (lane < VN) ? (Ereg + lsum_r) : -INFINITY;
            float m = Lv; int ai = lane;
            #pragma unroll
            for (int d = 1; d < 64; d <<= 1) {
                const float om = __shfl_xor(m, d);
                const int   oi = __shfl_xor(ai, d);
                if (om > m || (om == m && oi < ai)) { m = om; ai = oi; }
            }
            float e = (lane < VN) ? expf(Lv - m) : 0.f;
            #pragma unroll
            for (int d = 1; d < 64; d <<= 1) e += __shfl_xor(e, d);
            lps += -logf(e);                 // v = logits[argmax] - lse

            if (ai == BLANKI) { dirty = false; break; }
            if (slice == 0 && tid == 0) out[b*512 + pos] = (float)ai;
            pos++;
            jrow = ai;
            dirty = true;
        }
    }

    if (slice == 0 && tid == 0) {
        out[16384 + b] = (float)pos;   // n_symbols
        out[16416 + b] = lps;          // logp_sum
    }
}

extern "C" void kernel_launch(void* const* d_in, const int* in_sizes, int n_in,
                              void* d_out, int out_size, void* d_ws, size_t ws_size,
                              hipStream_t stream) {
    const float* x    = (const float*)d_in[0];
    const int* lens   = (const int*)  d_in[1];
    const float* emb  = (const float*)d_in[2];
    const float* Wih  = (const float*)d_in[3];
    const float* Whh  = (const float*)d_in[4];
    const float* bih  = (const float*)d_in[5];
    const float* bhh  = (const float*)d_in[6];
    const float* Wj   = (const float*)d_in[7];
    const float* bj   = (const float*)d_in[8];
    float* out = (float*)d_out;
    float* ws  = (float*)d_ws;

    float* E    = ws + E_OFF;
    float* P    = ws + P_OFF;
    u64*   xchg = (u64*)(ws + X_OFF);

    hipLaunchKernelGGL(k_enc,  dim3(1024), dim3(256), 0, stream, x, Wj, bj, E, xchg);
    hipLaunchKernelGGL(k_pred, dim3(29),   dim3(256), 0, stream, emb, Wih, bih, bhh, P);
    hipLaunchKernelGGL(k_dec,  dim3(256),  dim3(256), 0, stream,
                       lens, Whh, Wj, E, P, xchg, out);
}